// Round 8
// baseline (64.311 us; speedup 1.0000x reference)
//
#include <hip/hip_runtime.h>

#define NH 8
#define ND 64
#define NM 32
#define NCH 32   // sub-chunk size (re-chunked; math is associative)
#define NC 32    // num sub-chunks

// Full-wave (64-lane) sum reduction using DPP on the VALU pipe; result uniform.
__device__ __forceinline__ float wave_sum_bcast(float x) {
    float s = x;
    s += __int_as_float(__builtin_amdgcn_update_dpp(0, __float_as_int(s), 0x111, 0xf, 0xf, false));
    s += __int_as_float(__builtin_amdgcn_update_dpp(0, __float_as_int(s), 0x112, 0xf, 0xf, false));
    s += __int_as_float(__builtin_amdgcn_update_dpp(0, __float_as_int(s), 0x114, 0xf, 0xf, false));
    s += __int_as_float(__builtin_amdgcn_update_dpp(0, __float_as_int(s), 0x118, 0xf, 0xf, false));
    s += __int_as_float(__builtin_amdgcn_update_dpp(0, __float_as_int(s), 0x142, 0xa, 0xf, false));
    s += __int_as_float(__builtin_amdgcn_update_dpp(0, __float_as_int(s), 0x143, 0xc, 0xf, false));
    return __int_as_float(__builtin_amdgcn_readlane(__float_as_int(s), 63));
}

__device__ __forceinline__ float rdlane(float x, int l) {
    return __int_as_float(__builtin_amdgcn_readlane(__float_as_int(x), l));
}

// ---------------- Kernel 1: intra scan, register-resident, 2 m-rows/wave ----------------
__global__ __launch_bounds__(256) void intra_kernel(
    const float* __restrict__ A_bar, const float* __restrict__ K,
    const float* __restrict__ V, const float* __restrict__ beta,
    float* __restrict__ totalA, float* __restrict__ finalH)
{
    const int w  = blockIdx.x * 4 + (threadIdx.x >> 6);  // pair-wave id
    const int p  = w & 15;                               // m0 = p, m1 = p+16
    const int hh = (w >> 4) & (NH - 1);
    const int g  = w >> 7;
    const int lane = threadIdx.x & 63;
    const int lr   = lane & 31;                          // step this lane holds

    // K rows of the chunk -> 32 VGPRs (coalesced loads, L2-resident)
    float kreg[NCH];
    const float* Kp = K + ((g * NCH) * NH + hh) * 64 + lane;
#pragma unroll
    for (int t = 0; t < NCH; ++t) kreg[t] = Kp[t * (NH * 64)];

    // lane-distributed per-step scalars: lane lr holds step-lr values
    const int arow = ((g * NCH + lr) * NH + hh) * 64;
    const float2 A0 = *(const float2*)(A_bar + arow + 2 * p);
    const float2 A1 = *(const float2*)(A_bar + arow + 2 * (p + 16));
    const float2 Vv0 = *(const float2*)(V + arow + 2 * p);
    const float2 Vv1 = *(const float2*)(V + arow + 2 * (p + 16));
    const float  Bt = beta[(g * NCH + lr) * NH + hh];

    float hr0 = 0.f, hi0 = 0.f, hr1 = 0.f, hi1 = 0.f;
    float cr0 = 1.f, ci0 = 0.f, cr1 = 1.f, ci1 = 0.f;

#pragma unroll
    for (int t = 0; t < NCH; ++t) {
        const float ar0 = rdlane(A0.x, t),  ai0 = rdlane(A0.y, t);
        const float ar1 = rdlane(A1.x, t),  ai1 = rdlane(A1.y, t);
        const float vr0 = rdlane(Vv0.x, t), vi0 = rdlane(Vv0.y, t);
        const float vr1 = rdlane(Vv1.x, t), vi1 = rdlane(Vv1.y, t);
        const float b   = rdlane(Bt, t);
        const float kd  = kreg[t];
        const float bk  = b * kd;

        const float hkr0 = wave_sum_bcast(hr0 * kd);
        const float hki0 = wave_sum_bcast(hi0 * kd);
        const float hkr1 = wave_sum_bcast(hr1 * kd);
        const float hki1 = wave_sum_bcast(hi1 * kd);

        const float tr0 = hr0 - bk * hkr0, ti0 = hi0 - bk * hki0;
        hr0 = ar0 * tr0 - ai0 * ti0 + bk * vr0;
        hi0 = ar0 * ti0 + ai0 * tr0 + bk * vi0;
        const float tr1 = hr1 - bk * hkr1, ti1 = hi1 - bk * hki1;
        hr1 = ar1 * tr1 - ai1 * ti1 + bk * vr1;
        hi1 = ar1 * ti1 + ai1 * tr1 + bk * vi1;

        float n;
        n = cr0 * ar0 - ci0 * ai0; ci0 = cr0 * ai0 + ci0 * ar0; cr0 = n;
        n = cr1 * ar1 - ci1 * ai1; ci1 = cr1 * ai1 + ci1 * ar1; cr1 = n;
    }

    const int base = (g * NH + hh) * NM;
    const int f0 = (base + p) * ND + lane;
    const int f1 = (base + p + 16) * ND + lane;
    finalH[2 * f0]     = hr0;  finalH[2 * f0 + 1] = hi0;
    finalH[2 * f1]     = hr1;  finalH[2 * f1 + 1] = hi1;
    if (lane == 0) {
        totalA[2 * (base + p)]          = cr0;
        totalA[2 * (base + p) + 1]      = ci0;
        totalA[2 * (base + p + 16)]     = cr1;
        totalA[2 * (base + p + 16) + 1] = ci1;
    }
}

// ---------------- Kernel 2: inter-chunk serial scan, IN PLACE: finalH -> s_in ----------------
__global__ __launch_bounds__(256) void inter_kernel(
    const float* __restrict__ totalA, float* __restrict__ buf)
{
    const int tid = blockIdx.x * 256 + threadIdx.x;  // (hh*NM+m)*ND + d
    const int d  = tid & 63;
    const int hm = tid >> 6;                         // 0..255
    float sr = 0.f, si = 0.f;
#pragma unroll
    for (int g = 0; g < NC; ++g) {
        const int e    = g * 256 + hm;
        const int fidx = e * ND + d;
        const float fr = buf[2 * fidx];
        const float fi = buf[2 * fidx + 1];
        buf[2 * fidx]     = sr;
        buf[2 * fidx + 1] = si;
        const float ar = totalA[2 * e];
        const float ai = totalA[2 * e + 1];
        const float nsr = ar * sr - ai * si + fr;
        si = ar * si + ai * sr + fi;
        sr = nsr;
    }
}

// ---------------- Kernel 3: fused scan (state IS the output), register-resident ----------------
__global__ __launch_bounds__(256) void final_kernel(
    const float* __restrict__ A_bar, const float* __restrict__ K,
    const float* __restrict__ V, const float* __restrict__ beta,
    const float* __restrict__ s_in, float* __restrict__ Y)
{
    const int w  = blockIdx.x * 4 + (threadIdx.x >> 6);
    const int p  = w & 15;
    const int hh = (w >> 4) & (NH - 1);
    const int g  = w >> 7;
    const int lane = threadIdx.x & 63;
    const int lr   = lane & 31;

    float kreg[NCH];
    const float* Kp = K + ((g * NCH) * NH + hh) * 64 + lane;
#pragma unroll
    for (int t = 0; t < NCH; ++t) kreg[t] = Kp[t * (NH * 64)];

    const int arow = ((g * NCH + lr) * NH + hh) * 64;
    const float2 A0 = *(const float2*)(A_bar + arow + 2 * p);
    const float2 A1 = *(const float2*)(A_bar + arow + 2 * (p + 16));
    const float2 Vv0 = *(const float2*)(V + arow + 2 * p);
    const float2 Vv1 = *(const float2*)(V + arow + 2 * (p + 16));
    const float  Bt = beta[(g * NCH + lr) * NH + hh];

    const int base = (g * NH + hh) * NM;
    const int f0 = (base + p) * ND + lane;
    const int f1 = (base + p + 16) * ND + lane;
    float hr0 = s_in[2 * f0], hi0 = s_in[2 * f0 + 1];
    float hr1 = s_in[2 * f1], hi1 = s_in[2 * f1 + 1];
    const int base_l = g * NCH;

#pragma unroll
    for (int t = 0; t < NCH; ++t) {
        const float ar0 = rdlane(A0.x, t),  ai0 = rdlane(A0.y, t);
        const float ar1 = rdlane(A1.x, t),  ai1 = rdlane(A1.y, t);
        const float vr0 = rdlane(Vv0.x, t), vi0 = rdlane(Vv0.y, t);
        const float vr1 = rdlane(Vv1.x, t), vi1 = rdlane(Vv1.y, t);
        const float b   = rdlane(Bt, t);
        const float kd  = kreg[t];
        const float bk  = b * kd;

        const float hkr0 = wave_sum_bcast(hr0 * kd);
        const float hki0 = wave_sum_bcast(hi0 * kd);
        const float hkr1 = wave_sum_bcast(hr1 * kd);
        const float hki1 = wave_sum_bcast(hi1 * kd);

        const float tr0 = hr0 - bk * hkr0, ti0 = hi0 - bk * hki0;
        hr0 = ar0 * tr0 - ai0 * ti0 + bk * vr0;
        hi0 = ar0 * ti0 + ai0 * tr0 + bk * vi0;
        const float tr1 = hr1 - bk * hkr1, ti1 = hi1 - bk * hki1;
        hr1 = ar1 * tr1 - ai1 * ti1 + bk * vr1;
        hi1 = ar1 * ti1 + ai1 * tr1 + bk * vi1;

        // Y[b,l,h,2m,d]=Re, Y[b,l,h,2m+1,d]=Im — state IS the output
        const int ybase = ((base_l + t) * NH + hh) * (2 * NM) * ND + lane;
        __builtin_nontemporal_store(hr0, &Y[ybase + (2 * p) * ND]);
        __builtin_nontemporal_store(hi0, &Y[ybase + (2 * p + 1) * ND]);
        __builtin_nontemporal_store(hr1, &Y[ybase + (2 * (p + 16)) * ND]);
        __builtin_nontemporal_store(hi1, &Y[ybase + (2 * (p + 16) + 1) * ND]);
    }
}

extern "C" void kernel_launch(void* const* d_in, const int* in_sizes, int n_in,
                              void* d_out, int out_size, void* d_ws, size_t ws_size,
                              hipStream_t stream) {
    const float* A_bar = (const float*)d_in[0];
    const float* K     = (const float*)d_in[1];
    const float* V     = (const float*)d_in[2];
    const float* beta  = (const float*)d_in[3];
    float* Y = (float*)d_out;

    float* ws = (float*)d_ws;
    float* totalA = ws;                         // NC*NH*NM*2 = 16384 floats
    float* buf    = ws + 16384;                 // finalH/s_in in place: 1,048,576 floats

    const int nwave = NC * NH * (NM / 2);       // 4096 pair-waves
    intra_kernel<<<nwave / 4, 256, 0, stream>>>(A_bar, K, V, beta, totalA, buf);
    inter_kernel<<<(NH * NM * ND) / 256, 256, 0, stream>>>(totalA, buf);
    final_kernel<<<nwave / 4, 256, 0, stream>>>(A_bar, K, V, beta, buf, Y);
}

// Round 9
// 49.882 us; speedup vs baseline: 1.2893x; 1.2893x over previous
//
#include <hip/hip_runtime.h>

#define NH 8
#define ND 64
#define NM 32
#define NCH 32   // sub-chunk size (re-chunked; math is associative)
#define NC 32    // num sub-chunks

// ---- 64-lane reduce (DPP rows + readlane) — used by final_kernel ----
__device__ __forceinline__ float wave_sum_bcast(float x) {
    float s = x;
    s += __int_as_float(__builtin_amdgcn_update_dpp(0, __float_as_int(s), 0x111, 0xf, 0xf, false));
    s += __int_as_float(__builtin_amdgcn_update_dpp(0, __float_as_int(s), 0x112, 0xf, 0xf, false));
    s += __int_as_float(__builtin_amdgcn_update_dpp(0, __float_as_int(s), 0x114, 0xf, 0xf, false));
    s += __int_as_float(__builtin_amdgcn_update_dpp(0, __float_as_int(s), 0x118, 0xf, 0xf, false));
    s += __int_as_float(__builtin_amdgcn_update_dpp(0, __float_as_int(s), 0x142, 0xa, 0xf, false));
    s += __int_as_float(__builtin_amdgcn_update_dpp(0, __float_as_int(s), 0x143, 0xc, 0xf, false));
    return __int_as_float(__builtin_amdgcn_readlane(__float_as_int(s), 63));
}

// ---- 16-lane-group allreduce, pure VALU butterfly (no readlane) ----
// xor1: quad_perm [1,0,3,2]=0xB1; xor2: quad_perm [2,3,0,1]=0x4E;
// xor4: row_half_mirror=0x141;    xor8: row_mirror=0x140.
__device__ __forceinline__ float grp16_sum(float x) {
    x += __int_as_float(__builtin_amdgcn_update_dpp(0, __float_as_int(x), 0xB1, 0xf, 0xf, false));
    x += __int_as_float(__builtin_amdgcn_update_dpp(0, __float_as_int(x), 0x4E, 0xf, 0xf, false));
    x += __int_as_float(__builtin_amdgcn_update_dpp(0, __float_as_int(x), 0x141, 0xf, 0xf, false));
    x += __int_as_float(__builtin_amdgcn_update_dpp(0, __float_as_int(x), 0x140, 0xf, 0xf, false));
    return x;
}

// ---------------- Kernel 1: intra scan, 16-lane groups, 4 m-rows/wave ----------------
// Block = 512 threads (8 waves) handles one (g,hh) chunk fully (32 m-rows).
__global__ __launch_bounds__(512) void intra_kernel(
    const float* __restrict__ A_bar, const float* __restrict__ K,
    const float* __restrict__ V, const float* __restrict__ beta,
    float* __restrict__ totalA, float* __restrict__ finalH)
{
    __shared__ float K_p[NCH][ND];   // permuted: K_p[t][j*4+q] = K[t][j+16q]
    __shared__ float A_l[NCH][ND], V_l[NCH][ND];
    __shared__ float b_l[NCH];

    const int gh = blockIdx.x;       // g*NH + hh
    const int hh = gh & (NH - 1);
    const int g  = gh >> 3;
    const int tid = threadIdx.x;

#pragma unroll
    for (int rep = 0; rep < 4; ++rep) {
        const int flat = rep * 512 + tid;          // 0..2047
        const int t = flat >> 6, idx = flat & 63;
        const int row = ((g * NCH + t) * NH + hh) * 64;
        K_p[t][(idx & 15) * 4 + (idx >> 4)] = K[row + idx];
        A_l[t][idx] = A_bar[row + idx];
        V_l[t][idx] = V[row + idx];
    }
    if (tid < NCH) b_l[tid] = beta[(g * NCH + tid) * NH + hh];
    __syncthreads();

    const int lane = tid & 63;
    const int r = lane >> 4, j = lane & 15;
    const int m = (tid >> 6) * 4 + r;              // 0..31

    float hr[4] = {0.f, 0.f, 0.f, 0.f};
    float hi[4] = {0.f, 0.f, 0.f, 0.f};
    float cr = 1.f, ci = 0.f;

#pragma unroll 4
    for (int t = 0; t < NCH; ++t) {
        const float4 k4 = *(const float4*)(&K_p[t][j * 4]);
        const float2 a2 = *(const float2*)(&A_l[t][2 * m]);
        const float2 v2 = *(const float2*)(&V_l[t][2 * m]);
        const float  b  = b_l[t];

        float sr = (hr[0] * k4.x + hr[1] * k4.y) + (hr[2] * k4.z + hr[3] * k4.w);
        float si = (hi[0] * k4.x + hi[1] * k4.y) + (hi[2] * k4.z + hi[3] * k4.w);
        sr = grp16_sum(sr);
        si = grp16_sum(si);

        const float bk0 = b * k4.x, bk1 = b * k4.y, bk2 = b * k4.z, bk3 = b * k4.w;
        float tr, ti;
        tr = hr[0] - bk0 * sr; ti = hi[0] - bk0 * si;
        hr[0] = a2.x * tr - a2.y * ti + bk0 * v2.x;
        hi[0] = a2.x * ti + a2.y * tr + bk0 * v2.y;
        tr = hr[1] - bk1 * sr; ti = hi[1] - bk1 * si;
        hr[1] = a2.x * tr - a2.y * ti + bk1 * v2.x;
        hi[1] = a2.x * ti + a2.y * tr + bk1 * v2.y;
        tr = hr[2] - bk2 * sr; ti = hi[2] - bk2 * si;
        hr[2] = a2.x * tr - a2.y * ti + bk2 * v2.x;
        hi[2] = a2.x * ti + a2.y * tr + bk2 * v2.y;
        tr = hr[3] - bk3 * sr; ti = hi[3] - bk3 * si;
        hr[3] = a2.x * tr - a2.y * ti + bk3 * v2.x;
        hi[3] = a2.x * ti + a2.y * tr + bk3 * v2.y;

        const float n = cr * a2.x - ci * a2.y;
        ci = cr * a2.y + ci * a2.x;
        cr = n;
    }

    const int base = (g * NH + hh) * NM + m;
#pragma unroll
    for (int q = 0; q < 4; ++q) {
        const int d = j + 16 * q;
        *(float2*)(&finalH[2 * (base * ND + d)]) = make_float2(hr[q], hi[q]);
    }
    if (j == 0) {
        totalA[2 * base]     = cr;
        totalA[2 * base + 1] = ci;
    }
}

// ---------------- Kernel 2: inter-chunk serial scan, IN PLACE: finalH -> s_in ----------------
__global__ __launch_bounds__(256) void inter_kernel(
    const float* __restrict__ totalA, float* __restrict__ buf)
{
    const int tid = blockIdx.x * 256 + threadIdx.x;  // (hh*NM+m)*ND + d
    const int d  = tid & 63;
    const int hm = tid >> 6;                         // 0..255
    float sr = 0.f, si = 0.f;
#pragma unroll
    for (int g = 0; g < NC; ++g) {
        const int e    = g * 256 + hm;
        const int fidx = e * ND + d;
        const float fr = buf[2 * fidx];
        const float fi = buf[2 * fidx + 1];
        buf[2 * fidx]     = sr;
        buf[2 * fidx + 1] = si;
        const float ar = totalA[2 * e];
        const float ai = totalA[2 * e + 1];
        const float nsr = ar * sr - ai * si + fr;
        si = ar * si + ai * sr + fi;
        sr = nsr;
    }
}

// ---- Cooperative stage of one (g,hh) chunk into LDS (256-thread blocks) ----
__device__ __forceinline__ void stage_chunk(
    const float* __restrict__ A_bar, const float* __restrict__ K,
    const float* __restrict__ V, const float* __restrict__ beta,
    int g, int hh,
    float (*K_lds)[ND], float (*A_lds)[ND], float (*V_lds)[ND], float* b_lds)
{
    const int tid = threadIdx.x;              // 256 threads
    const int t   = tid >> 3;                 // 0..31
    const int i   = tid & 7;                  // 0..7 -> 8 floats each
    const int l   = g * NCH + t;
    const int row = (l * NH + hh) * 64;
    const float4 k4a = *(const float4*)(K + row + i * 8);
    const float4 k4b = *(const float4*)(K + row + i * 8 + 4);
    const float4 a4a = *(const float4*)(A_bar + row + i * 8);
    const float4 a4b = *(const float4*)(A_bar + row + i * 8 + 4);
    const float4 v4a = *(const float4*)(V + row + i * 8);
    const float4 v4b = *(const float4*)(V + row + i * 8 + 4);
    *(float4*)(&K_lds[t][i * 8])     = k4a;
    *(float4*)(&K_lds[t][i * 8 + 4]) = k4b;
    *(float4*)(&A_lds[t][i * 8])     = a4a;
    *(float4*)(&A_lds[t][i * 8 + 4]) = a4b;
    *(float4*)(&V_lds[t][i * 8])     = v4a;
    *(float4*)(&V_lds[t][i * 8 + 4]) = v4b;
    if (tid < NCH) b_lds[tid] = beta[(g * NCH + tid) * NH + hh];
    __syncthreads();
}

// ---------------- Kernel 3: fused scan (state IS the output), 2 m-rows/wave ----------------
__global__ __launch_bounds__(256) void final_kernel(
    const float* __restrict__ A_bar, const float* __restrict__ K,
    const float* __restrict__ V, const float* __restrict__ beta,
    const float* __restrict__ s_in, float* __restrict__ Y)
{
    __shared__ float K_lds[NCH][ND], A_lds[NCH][ND], V_lds[NCH][ND], b_lds[NCH];
    const int w  = blockIdx.x * 4 + (threadIdx.x >> 6);
    const int p  = w & 15;
    const int hh = (w >> 4) & (NH - 1);
    const int g  = w >> 7;
    const int lane = threadIdx.x & 63;

    stage_chunk(A_bar, K, V, beta, g, hh, K_lds, A_lds, V_lds, b_lds);

    const int base = (g * NH + hh) * NM;
    const int f0 = (base + p) * ND + lane;
    const int f1 = (base + p + 16) * ND + lane;
    float hr0 = s_in[2 * f0], hi0 = s_in[2 * f0 + 1];
    float hr1 = s_in[2 * f1], hi1 = s_in[2 * f1 + 1];
    const int base_l = g * NCH;

#pragma unroll 4
    for (int t = 0; t < NCH; ++t) {
        const float  kd = K_lds[t][lane];
        const float  b  = b_lds[t];
        const float2 a0 = *(const float2*)(&A_lds[t][2 * p]);
        const float2 v0 = *(const float2*)(&V_lds[t][2 * p]);
        const float2 a1 = *(const float2*)(&A_lds[t][2 * (p + 16)]);
        const float2 v1 = *(const float2*)(&V_lds[t][2 * (p + 16)]);
        const float  bk = b * kd;

        const float hkr0 = wave_sum_bcast(hr0 * kd);
        const float hki0 = wave_sum_bcast(hi0 * kd);
        const float hkr1 = wave_sum_bcast(hr1 * kd);
        const float hki1 = wave_sum_bcast(hi1 * kd);

        const float tr0 = hr0 - bk * hkr0, ti0 = hi0 - bk * hki0;
        hr0 = a0.x * tr0 - a0.y * ti0 + bk * v0.x;
        hi0 = a0.x * ti0 + a0.y * tr0 + bk * v0.y;
        const float tr1 = hr1 - bk * hkr1, ti1 = hi1 - bk * hki1;
        hr1 = a1.x * tr1 - a1.y * ti1 + bk * v1.x;
        hi1 = a1.x * ti1 + a1.y * tr1 + bk * v1.y;

        // Y[b,l,h,2m,d]=Re, Y[b,l,h,2m+1,d]=Im — state IS the output
        const int ybase = ((base_l + t) * NH + hh) * (2 * NM) * ND + lane;
        __builtin_nontemporal_store(hr0, &Y[ybase + (2 * p) * ND]);
        __builtin_nontemporal_store(hi0, &Y[ybase + (2 * p + 1) * ND]);
        __builtin_nontemporal_store(hr1, &Y[ybase + (2 * (p + 16)) * ND]);
        __builtin_nontemporal_store(hi1, &Y[ybase + (2 * (p + 16) + 1) * ND]);
    }
}

extern "C" void kernel_launch(void* const* d_in, const int* in_sizes, int n_in,
                              void* d_out, int out_size, void* d_ws, size_t ws_size,
                              hipStream_t stream) {
    const float* A_bar = (const float*)d_in[0];
    const float* K     = (const float*)d_in[1];
    const float* V     = (const float*)d_in[2];
    const float* beta  = (const float*)d_in[3];
    float* Y = (float*)d_out;

    float* ws = (float*)d_ws;
    float* totalA = ws;                         // NC*NH*NM*2 = 16384 floats
    float* buf    = ws + 16384;                 // finalH/s_in in place: 1,048,576 floats

    intra_kernel<<<NC * NH, 512, 0, stream>>>(A_bar, K, V, beta, totalA, buf);
    inter_kernel<<<(NH * NM * ND) / 256, 256, 0, stream>>>(totalA, buf);
    const int nwave = NC * NH * (NM / 2);       // 4096 pair-waves
    final_kernel<<<nwave / 4, 256, 0, stream>>>(A_bar, K, V, beta, buf, Y);
}